// Round 7
// baseline (527.014 us; speedup 1.0000x reference)
//
#include <hip/hip_runtime.h>

#define BB 128
#define CC 272
#define TT 1024
#define DD 270
#define KK 32
#define NKC 9              // k-chunks of 32 (C padded to 288)
#define NMT 17             // d-tiles of 16 (D padded to 272)
#define MP 272
#define WUNITS ((NKC * NMT * 1024) / 16)   // 9792 16B units = 156,672 B

typedef __attribute__((ext_vector_type(8))) short s16x8;
typedef __attribute__((ext_vector_type(4))) float f32x4;

__device__ __forceinline__ unsigned short f2bf(float f) {
  unsigned int u = __builtin_bit_cast(unsigned int, f);
  u += 0x7fffu + ((u >> 16) & 1u);   // round-to-nearest-even
  return (unsigned short)(u >> 16);
}

// ---------------- Kernel 1: partial A[d][c], 4-way k-split ----------------
__global__ __launch_bounds__(288) void phaseA_kernel(
    const float* __restrict__ loc, const float* __restrict__ z_re,
    const float* __restrict__ z_im, float* __restrict__ A) {
  const int d = blockIdx.x;
  const int p = blockIdx.y;          // k-part 0..3
  const int c = threadIdx.x;
  if (c >= CC) return;
  const float TWO_PI = 6.28318530717958647692f;
  float x = loc[2 * c], y = loc[2 * c + 1];
  float sx, cx, sy, cyv;
  sincosf(TWO_PI * x, &sx, &cx);
  sincosf(TWO_PI * y, &sy, &cyv);
  float cl[KK], sl[KK];
  cl[0] = 1.f; sl[0] = 0.f;
#pragma unroll
  for (int l = 1; l < KK; ++l) {
    cl[l] = cl[l - 1] * cyv - sl[l - 1] * sy;
    sl[l] = sl[l - 1] * cyv + cl[l - 1] * sy;
  }
  const int k0 = p * 8;
  float sk, ck;
  sincosf(TWO_PI * (float)k0 * x, &sk, &ck);
  const float* zr = z_re + (size_t)d * (KK * KK) + k0 * KK;
  const float* zi = z_im + (size_t)d * (KK * KK) + k0 * KK;
  float acc = 0.f;
  for (int k = 0; k < 8; ++k) {
    float s_rc = 0.f, s_rs = 0.f, s_ic = 0.f, s_is = 0.f;
#pragma unroll
    for (int l = 0; l < KK; ++l) {
      float vr = zr[k * KK + l];   // wave-uniform -> scalar loads
      float vi = zi[k * KK + l];
      s_rc += vr * cl[l];
      s_rs += vr * sl[l];
      s_ic += vi * cl[l];
      s_is += vi * sl[l];
    }
    acc += ck * (s_rc + s_is) + sk * (s_ic - s_rs);
    float nck = ck * cx - sk * sx;
    sk = sk * cx + ck * sx;
    ck = nck;
  }
  atomicAdd(&A[d * CC + c], acc);
}

// ---------------- Kernel 2: row softmax -> bf16 w, MFMA-fragment layout ---
// Frag (kc, mt) = 1024 B: lane l = hi*16 + m holds w[mt*16+m][kc*32+hi*8+j],
// j=0..7 — the A-operand layout of mfma_f32_16x16x32_bf16 (harness-verified
// rounds 0-2,4,5). Frags contiguous: GEMM stages the buffer as a flat
// memcpy into LDS and reads each frag as ds_read_b128 at base + lane*16 —
// lane-sequential 16 B = bank-conflict-free. Pads (d>=270, c>=272) are zero.
__global__ __launch_bounds__(64) void softmax_kernel(
    const float* __restrict__ A, unsigned short* __restrict__ wb) {
  const int d = blockIdx.x;   // 0..271
  const int lane = threadIdx.x;
  const bool live = (d < DD);
  float v[5];
  float inv = 0.f;
  if (live) {
    float m = -3.0e38f;
#pragma unroll
    for (int j = 0; j < 5; ++j) {
      int cidx = lane + 64 * j;
      v[j] = (cidx < CC) ? A[(size_t)d * CC + cidx] : -3.0e38f;
      m = fmaxf(m, v[j]);
    }
#pragma unroll
    for (int off = 32; off >= 1; off >>= 1) m = fmaxf(m, __shfl_xor(m, off, 64));
    float s = 0.f;
#pragma unroll
    for (int j = 0; j < 5; ++j) {
      int cidx = lane + 64 * j;
      v[j] = (cidx < CC) ? expf(v[j] - m) : 0.f;
      s += v[j];
    }
#pragma unroll
    for (int off = 32; off >= 1; off >>= 1) s += __shfl_xor(s, off, 64);
    inv = 1.f / s;
  }
  const int mt = d >> 4, mrow = d & 15;
#pragma unroll
  for (int j = 0; j < 5; ++j) {
    int kk = lane + 64 * j;      // column index incl. padding
    if (kk < NKC * KK) {
      unsigned short val = 0;
      if (live && kk < CC) val = f2bf(v[j] * inv);
      int kc = kk >> 5, hi = (kk >> 3) & 3, jj = kk & 7;
      wb[((size_t)(kc * NMT + mt) << 9) + (((hi << 4) | mrow) << 3) + jj] = val;
    }
  }
}

// ---------------- Kernel 3: out[b,d,t] = sum_c w[d,c] * X[b,c,t] ----------
// ONE block-round: grid 256 = 128 b x 2 t-tiles of 512, 1024 threads =
// 16 waves, 1 block/CU (LDS 156 KB). w staged once as flat memcpy into LDS
// (frag-linear layout -> conflict-free ds_read_b128 at base + lane*16, each
// A-read feeds 2 MFMAs), X via 3-deep register prefetch, single barrier.
// __launch_bounds__(1024, 1): round 6 omitted the min-waves arg and the
// compiler budgeted ~200 unified regs/wave -> spilled the 136-reg acc to
// scratch (VGPR_Count 64, hbm_bytes 1.13 GB = 5x, MfmaUtil 2.5%). With
// ",1" the budget is 512/wave; acc(136 AGPR) + ~110 VGPR fits, zero spill.
// LDS caps residency at 1 block/CU anyway, so nothing is lost.
__global__ __launch_bounds__(1024, 1) void gemm_kernel(
    const float* __restrict__ X, const unsigned short* __restrict__ wb,
    float* __restrict__ out) {
  __shared__ unsigned short wlds[NKC * NMT * 512];   // 156,672 B
  const int bid = blockIdx.x;
  const int b = bid >> 1;
  const int t0 = (bid & 1) << 9;      // 512-wide t tile
  const int tid = threadIdx.x;
  const int lane = tid & 63;
  const int wv = tid >> 6;            // 0..15
  const int q = lane >> 4;            // k-subgroup 0..3
  const int r16 = lane & 15;
  const int csub = q << 3;

  // ---- stage all of w: 9792 x 16B over 1024 threads (10 rounds) ----
  {
    const char* src = (const char*)wb;
    char* dst = (char*)wlds;
#pragma unroll
    for (int r = 0; r < 10; ++r) {
      int idx = tid + r * 1024;
      if (idx < WUNITS) {
        __builtin_amdgcn_global_load_lds(
            (const __attribute__((address_space(1))) unsigned int*)(src + idx * 16),
            (__attribute__((address_space(3))) unsigned int*)(dst + idx * 16),
            16, 0, 0);
      }
    }
  }

  f32x4 acc[NMT][2];
#pragma unroll
  for (int i = 0; i < NMT; ++i)
#pragma unroll
    for (int f = 0; f < 2; ++f) acc[i][f] = (f32x4){0.f, 0.f, 0.f, 0.f};

  const float* Xb = X + (size_t)b * (CC * TT) + t0 + wv * 32 + r16;

// DST[j] = frag0 elem j (t offset 0), DST[8+j] = frag1 elem j (t offset 16)
#define XLOAD(DST, KC)                                                  \
  {                                                                     \
    _Pragma("unroll") for (int j = 0; j < 8; ++j) {                     \
      int c_ = (KC) * KK + csub + j;                                    \
      float v0_ = 0.f, v1_ = 0.f;                                       \
      if ((KC) < 8 || c_ < CC) {                                        \
        v0_ = Xb[(size_t)c_ * TT];                                      \
        v1_ = Xb[(size_t)c_ * TT + 16];                                 \
      }                                                                 \
      DST[j] = v0_;                                                     \
      DST[8 + j] = v1_;                                                 \
    }                                                                   \
  }

  float x0[16], x1[16], x2[16];
  XLOAD(x0, 0);
  XLOAD(x1, 1);
  XLOAD(x2, 2);

  __syncthreads();   // single barrier: w staged (drains vmcnt once)

#define BODY(KC, XC)                                                          \
  {                                                                           \
    union { unsigned int u[4]; s16x8 v; } bf[2];                              \
    _Pragma("unroll") for (int f = 0; f < 2; ++f)                             \
        _Pragma("unroll") for (int p = 0; p < 4; ++p)                         \
        bf[f].u[p] = (unsigned int)f2bf(XC[f * 8 + 2 * p]) |                  \
                     ((unsigned int)f2bf(XC[f * 8 + 2 * p + 1]) << 16);       \
    if ((KC) + 3 < NKC) { XLOAD(XC, (KC) + 3); }                              \
    const char* wch_ = (const char*)wlds + (size_t)(KC) * (NMT * 1024) +      \
                       (size_t)lane * 16;                                     \
    _Pragma("unroll") for (int mt = 0; mt < NMT; ++mt) {                      \
      s16x8 af_ = *(const s16x8*)(wch_ + mt * 1024);                          \
      acc[mt][0] = __builtin_amdgcn_mfma_f32_16x16x32_bf16(af_, bf[0].v,      \
                                                           acc[mt][0], 0, 0, 0); \
      acc[mt][1] = __builtin_amdgcn_mfma_f32_16x16x32_bf16(af_, bf[1].v,      \
                                                           acc[mt][1], 0, 0, 0); \
    }                                                                         \
  }

  BODY(0, x0) BODY(1, x1) BODY(2, x2)
  BODY(3, x0) BODY(4, x1) BODY(5, x2)
  BODY(6, x0) BODY(7, x1) BODY(8, x2)

#undef BODY
#undef XLOAD

  // ---- epilogue: D row = mt*16 + q*4 + r, col t = t0 + wv*32 + f*16 + r16 --
  float* op = out + (size_t)b * (DD * TT) + t0 + wv * 32 + r16;
#pragma unroll
  for (int mt = 0; mt < NMT; ++mt) {
#pragma unroll
    for (int f = 0; f < 2; ++f)
#pragma unroll
      for (int r = 0; r < 4; ++r) {
        const int drow = mt * 16 + q * 4 + r;
        if (drow < DD) op[(size_t)drow * TT + (f << 4)] = acc[mt][f][r];
      }
  }
}

extern "C" void kernel_launch(void* const* d_in, const int* in_sizes, int n_in,
                              void* d_out, int out_size, void* d_ws, size_t ws_size,
                              hipStream_t stream) {
  const float* X = (const float*)d_in[0];
  const float* loc = (const float*)d_in[1];
  const float* z_re = (const float*)d_in[2];
  const float* z_im = (const float*)d_in[3];
  float* out = (float*)d_out;

  float* A = (float*)d_ws;                                        // 293,760 B
  unsigned short* wbf = (unsigned short*)((char*)d_ws + 294912);  // 156,672 B

  hipMemsetAsync(A, 0, DD * CC * sizeof(float), stream);
  phaseA_kernel<<<dim3(DD, 4), 288, 0, stream>>>(loc, z_re, z_im, A);
  softmax_kernel<<<MP, 64, 0, stream>>>(A, wbf);
  gemm_kernel<<<BB * (TT / 512), 1024, 0, stream>>>(X, wbf, out);
}

// Round 8
// 283.237 us; speedup vs baseline: 1.8607x; 1.8607x over previous
//
#include <hip/hip_runtime.h>

#define BB 128
#define CC 272
#define TT 1024
#define DD 270
#define KK 32
#define NKC 9              // k-chunks of 32 (C padded to 288)
#define NMT 17             // d-tiles of 16 (D padded to 272)
#define WUNITS ((NKC * NMT * 1024) / 16)   // 9792 16B units = 156,672 B

typedef __attribute__((ext_vector_type(8))) short s16x8;
typedef __attribute__((ext_vector_type(4))) float f32x4;
typedef __attribute__((ext_vector_type(2))) float f32x2;

__device__ __forceinline__ unsigned short f2bf(float f) {
  unsigned int u = __builtin_bit_cast(unsigned int, f);
  u += 0x7fffu + ((u >> 16) & 1u);   // round-to-nearest-even
  return (unsigned short)(u >> 16);
}

// ------- Kernel 1 (fused): A-row compute + row softmax -> bf16 w ----------
// One block per d-row (272 blocks x 320 threads; thread = c). Replaces the
// old {memset A, 1080-block atomicAdd phaseA, softmax kernel}: no atomics,
// no A round-trip, 2 fewer dispatches. k-loop runs all 32 k in-thread but
// re-seeds sincos every 8 k — bitwise-identical rotation arithmetic to the
// verified 4-way-split kernel. Block softmax via wave shfl + LDS reduce.
// w frag layout (verified rounds 0-2,4,5): frag (kc, mt) = 1024 B, lane
// l = hi*16 + m holds w[mt*16+m][kc*32+hi*8+j]; pads (d>=270, c>=272) zero.
__global__ __launch_bounds__(320) void phaseA_softmax_kernel(
    const float* __restrict__ loc, const float* __restrict__ z_re,
    const float* __restrict__ z_im, unsigned short* __restrict__ wb) {
  const int d = blockIdx.x;        // 0..271
  const int tid = threadIdx.x;     // 0..319
  const int c = tid;
  const bool live = (d < DD) && (c < CC);
  const float TWO_PI = 6.28318530717958647692f;

  float acc = 0.f;
  if (live) {
    float x = loc[2 * c], y = loc[2 * c + 1];
    float sx, cx, sy, cyv;
    sincosf(TWO_PI * x, &sx, &cx);
    sincosf(TWO_PI * y, &sy, &cyv);
    float cl[KK], sl[KK];
    cl[0] = 1.f; sl[0] = 0.f;
#pragma unroll
    for (int l = 1; l < KK; ++l) {
      cl[l] = cl[l - 1] * cyv - sl[l - 1] * sy;
      sl[l] = sl[l - 1] * cyv + cl[l - 1] * sy;
    }
    for (int p = 0; p < 4; ++p) {
      const int k0 = p * 8;
      float sk, ck;
      sincosf(TWO_PI * (float)k0 * x, &sk, &ck);   // exact re-seed per part
      const float* zr = z_re + (size_t)d * (KK * KK) + k0 * KK;
      const float* zi = z_im + (size_t)d * (KK * KK) + k0 * KK;
      for (int k = 0; k < 8; ++k) {
        float s_rc = 0.f, s_rs = 0.f, s_ic = 0.f, s_is = 0.f;
#pragma unroll
        for (int l = 0; l < KK; ++l) {
          float vr = zr[k * KK + l];   // wave-uniform -> scalar loads
          float vi = zi[k * KK + l];
          s_rc += vr * cl[l];
          s_rs += vr * sl[l];
          s_ic += vi * cl[l];
          s_is += vi * sl[l];
        }
        acc += ck * (s_rc + s_is) + sk * (s_ic - s_rs);
        float nck = ck * cx - sk * sx;
        sk = sk * cx + ck * sx;
        ck = nck;
      }
    }
  }

  // ---- block softmax over c (320 threads = 5 waves) ----
  __shared__ float redm[5], reds[5];
  float m = live ? acc : -3.0e38f;
#pragma unroll
  for (int off = 32; off >= 1; off >>= 1) m = fmaxf(m, __shfl_xor(m, off, 64));
  if ((tid & 63) == 0) redm[tid >> 6] = m;
  __syncthreads();
  const float mAll = fmaxf(fmaxf(fmaxf(redm[0], redm[1]),
                                 fmaxf(redm[2], redm[3])), redm[4]);
  float e = live ? expf(acc - mAll) : 0.f;
  float s = e;
#pragma unroll
  for (int off = 32; off >= 1; off >>= 1) s += __shfl_xor(s, off, 64);
  if ((tid & 63) == 0) reds[tid >> 6] = s;
  __syncthreads();
  const float sAll = reds[0] + reds[1] + reds[2] + reds[3] + reds[4];
  const float inv = 1.f / sAll;    // dead-row blocks: unused (val forced 0)

  if (c < NKC * KK) {              // kk 0..287: includes zero pads
    unsigned short val = live ? f2bf(e * inv) : (unsigned short)0;
    const int mt = d >> 4, mrow = d & 15;
    const int kc = c >> 5, hi = (c >> 3) & 3, jj = c & 7;
    wb[((size_t)(kc * NMT + mt) << 9) + (((hi << 4) | mrow) << 3) + jj] = val;
  }
}

// ---------------- Kernel 2: out[b,d,t] = sum_c w[d,c] * X[b,c,t] ----------
// Round-5 verified structure (best measured: total 309, gemm ~85): 512
// threads = 8 waves, block = (b, 256-t tile), wave owns 32 t, whole w staged
// once into LDS (frag-linear -> conflict-free ds_read_b128, each A-read
// feeds 2 MFMAs), 3-deep X register prefetch, one barrier, XCD swizzle.
// ONE change: paired-t frags. Frag f, column n carries t = wv*32 + 2n + f
// (was n, n+16). Each lane then loads one float2 (2 consecutive t) per
// c-row — 8 load instrs/chunk instead of 16, each 4x 128-B full-line
// requests (was 4x 64-B) — and the epilogue stores {acc0[r],acc1[r]} as one
// float2 = full-line writes. Doubles bytes-per-request on both directions;
// attacks the ~2.3 TB/s request-granularity plateau. Pure in-lane column
// permutation: w layout, MFMA usage, row mapping all unchanged.
__global__ __launch_bounds__(512, 2) void gemm_kernel(
    const float* __restrict__ X, const unsigned short* __restrict__ wb,
    float* __restrict__ out) {
  __shared__ unsigned short wlds[NKC * NMT * 512];   // 156,672 B
  const int bid = blockIdx.x;
  const int L = (bid & 7) * 64 + (bid >> 3);   // XCD swizzle (512%8==0, bijective)
  const int b = L >> 2;
  const int t0 = (L & 3) << 8;                 // 256-wide t tile
  const int tid = threadIdx.x;
  const int lane = tid & 63;
  const int wv = tid >> 6;            // 0..7
  const int q = lane >> 4;            // k-subgroup 0..3
  const int r16 = lane & 15;
  const int csub = q << 3;

  // ---- stage all of w: 9792 x 16B over 512 threads (20 rounds) ----
  {
    const char* src = (const char*)wb;
    char* dst = (char*)wlds;
#pragma unroll
    for (int r = 0; r < 20; ++r) {
      int idx = tid + r * 512;
      if (idx < WUNITS) {
        __builtin_amdgcn_global_load_lds(
            (const __attribute__((address_space(1))) unsigned int*)(src + idx * 16),
            (__attribute__((address_space(3))) unsigned int*)(dst + idx * 16),
            16, 0, 0);
      }
    }
  }

  f32x4 acc[NMT][2];
#pragma unroll
  for (int i = 0; i < NMT; ++i)
#pragma unroll
    for (int f = 0; f < 2; ++f) acc[i][f] = (f32x4){0.f, 0.f, 0.f, 0.f};

  // paired-t base: lane covers t = t0 + wv*32 + 2*r16 (+1)
  const float* Xb = X + (size_t)b * (CC * TT) + t0 + wv * 32 + 2 * r16;

// DST[j] = frag0 elem j (even t), DST[8+j] = frag1 elem j (odd t)
#define XLOAD(DST, KC)                                                  \
  {                                                                     \
    _Pragma("unroll") for (int j = 0; j < 8; ++j) {                     \
      int c_ = (KC) * KK + csub + j;                                    \
      f32x2 v_ = (f32x2){0.f, 0.f};                                     \
      if ((KC) < 8 || c_ < CC)                                          \
        v_ = *(const f32x2*)(Xb + (size_t)c_ * TT);                     \
      DST[j] = v_[0];                                                   \
      DST[8 + j] = v_[1];                                               \
    }                                                                   \
  }

  float x0[16], x1[16], x2[16];
  XLOAD(x0, 0);
  XLOAD(x1, 1);
  XLOAD(x2, 2);

  __syncthreads();   // single barrier: w staged (drains vmcnt once)

#define BODY(KC, XC)                                                          \
  {                                                                           \
    union { unsigned int u[4]; s16x8 v; } bf[2];                              \
    _Pragma("unroll") for (int f = 0; f < 2; ++f)                             \
        _Pragma("unroll") for (int p = 0; p < 4; ++p)                         \
        bf[f].u[p] = (unsigned int)f2bf(XC[f * 8 + 2 * p]) |                  \
                     ((unsigned int)f2bf(XC[f * 8 + 2 * p + 1]) << 16);       \
    if ((KC) + 3 < NKC) { XLOAD(XC, (KC) + 3); }                              \
    const char* wch_ = (const char*)wlds + (size_t)(KC) * (NMT * 1024) +      \
                       (size_t)lane * 16;                                     \
    _Pragma("unroll") for (int mt = 0; mt < NMT; ++mt) {                      \
      s16x8 af_ = *(const s16x8*)(wch_ + mt * 1024);                          \
      acc[mt][0] = __builtin_amdgcn_mfma_f32_16x16x32_bf16(af_, bf[0].v,      \
                                                           acc[mt][0], 0, 0, 0); \
      acc[mt][1] = __builtin_amdgcn_mfma_f32_16x16x32_bf16(af_, bf[1].v,      \
                                                           acc[mt][1], 0, 0, 0); \
    }                                                                         \
  }

  BODY(0, x0) BODY(1, x1) BODY(2, x2)
  BODY(3, x0) BODY(4, x1) BODY(5, x2)
  BODY(6, x0) BODY(7, x1) BODY(8, x2)

#undef BODY
#undef XLOAD

  // ---- epilogue: D row = mt*16 + q*4 + r; cols (2*r16, 2*r16+1) as float2 --
  float* op = out + (size_t)b * (DD * TT) + t0 + wv * 32 + 2 * r16;
#pragma unroll
  for (int mt = 0; mt < NMT; ++mt) {
#pragma unroll
    for (int r = 0; r < 4; ++r) {
      const int drow = mt * 16 + q * 4 + r;
      if (drow < DD) {
        f32x2 st = (f32x2){acc[mt][0][r], acc[mt][1][r]};
        *(f32x2*)(op + (size_t)drow * TT) = st;
      }
    }
  }
}

extern "C" void kernel_launch(void* const* d_in, const int* in_sizes, int n_in,
                              void* d_out, int out_size, void* d_ws, size_t ws_size,
                              hipStream_t stream) {
  const float* X = (const float*)d_in[0];
  const float* loc = (const float*)d_in[1];
  const float* z_re = (const float*)d_in[2];
  const float* z_im = (const float*)d_in[3];
  float* out = (float*)d_out;

  unsigned short* wbf = (unsigned short*)d_ws;   // 156,672 B

  phaseA_softmax_kernel<<<NMT * 16, 320, 0, stream>>>(loc, z_re, z_im, wbf);
  gemm_kernel<<<BB * (TT / 256), 512, 0, stream>>>(X, wbf, out);
}